// Round 13
// baseline (175.671 us; speedup 1.0000x reference)
//
#include <hip/hip_runtime.h>

#define TT    512
#define WW    257
#define HWSZ  (WW*WW)          // 66049
#define IMG2  (2*HWSZ)         // time stride in `output` (2 channels)
#define SCALE 3.5682482323055424f   // DT^-0.5 / gamma(1.5)
#define KD    163.84f               // KAPPA / DX^2

typedef short bf16x8 __attribute__((ext_vector_type(8)));
typedef short bf16x4 __attribute__((ext_vector_type(4)));
typedef float f32x4  __attribute__((ext_vector_type(4)));

__device__ __forceinline__ float wf(int j) {
    return sqrtf((float)(j + 1)) - sqrtf((float)j);
}
__device__ __forceinline__ float mcoef(int i, int k) {
    if (i == 0 || k > i) return 0.f;
    if (k == i) return 1.f;
    if (k == 0) return -wf(i - 1);
    int d = i - k;
    return wf(d) - wf(d - 1);
}
__device__ __forceinline__ unsigned short f2b(float f) {
    unsigned u = __float_as_uint(f);
    return (unsigned short)((u + 0x7FFFu + ((u >> 16) & 1u)) >> 16);
}
__device__ __forceinline__ float b2f(unsigned short h) {
    return __uint_as_float(((unsigned)h) << 16);
}

// ---- kernel 1: M as bf16 [512][512] (L2-resident)
__global__ __launch_bounds__(256)
void build_m(unsigned short* __restrict__ M) {
    int i = blockIdx.x;
    for (int k = threadIdx.x; k < TT; k += 256)
        M[i * TT + k] = f2b(mcoef(i, k));
}

// ---- kernel 2: prestage. grid 256 = 64 t-groups x 4 y-strips. 512 thr = 8 waves,
// wave w owns t = 8*tg + w. Reads are LONG CONTIGUOUS streams (rows in sequence).
// Outputs:
//   uT tiled [pxblk 1020][kg=t>>3 64][pxl 64][t&7 8] bf16  (1KB-contig writes)
//   sB [pxblk][t 512][pxl 64] bf16                          (128B full-line runs)
__global__ __launch_bounds__(512, 2)
void prestage(const float* __restrict__ uin, const float* __restrict__ f1p,
              const float* __restrict__ lapk,
              unsigned short* __restrict__ uT, unsigned short* __restrict__ sB)
{
    __shared__ unsigned short us[2][8][264];   // [buf][t-local][px]

    const int tid = threadIdx.x, w = tid >> 6, l = tid & 63;
    const int tg  = blockIdx.x >> 2;           // t-group 0..63
    const int ys  = blockIdx.x & 3;            // y-strip 0..3
    const int t   = 8 * tg + w;
    const int yo0 = 64 * ys + 1;
    const int NY  = (ys < 3) ? 64 : 63;        // output rows in strip
    const float ka = lapk[0], kb = lapk[1], kc = lapk[4];
    const float* ub = uin + (size_t)t * IMG2;
    const float* fb = f1p + (size_t)t * HWSZ;

    float r0[5], r1[5], r2[5];
    {
        const float* p = ub + (size_t)(yo0 - 1) * WW;
        #pragma unroll
        for (int c = 0; c < 4; ++c) r0[c] = p[64 * c + l];
        r0[4] = p[256 + l];
        p += WW;
        #pragma unroll
        for (int c = 0; c < 4; ++c) r1[c] = p[64 * c + l];
        r1[4] = p[256 + l];
    }

    for (int i = 0; i <= NY; ++i) {
        const int yo = yo0 + i;
        if (i < NY) {
            // load row yo+1 (contiguous 1KB) + f1 row yo
            const float* p = ub + (size_t)(yo + 1) * WW;
            #pragma unroll
            for (int c = 0; c < 4; ++c) r2[c] = p[64 * c + l];
            r2[4] = p[256 + l];
            float F[4];
            #pragma unroll
            for (int c = 0; c < 4; ++c) F[c] = fb[(size_t)yo * WW + 64 * c + l + 1];

            float P[5], Q[5];
            #pragma unroll
            for (int c = 0; c < 5; ++c) { P[c] = r0[c] + r2[c]; Q[c] = fmaf(ka, P[c], kb * r1[c]); }

            const int buf = i & 1;
            #pragma unroll
            for (int c = 0; c < 4; ++c) {
                // lane l outputs pixel column xl = 64c + l  (image x = xl+1)
                float Qn = (c < 3) ? Q[c + 1] : Q[4];
                float Pn = (c < 3) ? P[c + 1] : P[4];
                float Un = (c < 3) ? r1[c + 1] : r1[4];
                float q2  = __shfl(Q[c], l + 2, 64);
                float qn0 = __shfl(Qn, 0, 64), qn1 = __shfl(Qn, 1, 64);
                q2 = (l == 62) ? qn0 : (l == 63) ? qn1 : q2;
                float p1 = __shfl(P[c], l + 1, 64);
                float u1 = __shfl(r1[c], l + 1, 64);
                float pn0 = __shfl(Pn, 0, 64), un0 = __shfl(Un, 0, 64);
                p1 = (l == 63) ? pn0 : p1;
                u1 = (l == 63) ? un0 : u1;
                float lap = Q[c] + q2 + fmaf(kb, p1, kc * u1);
                float s   = u1 - fmaf(KD, lap, F[c]);
                bool pad = (c == 3) && (l == 63);           // xl == 255
                unsigned short uu = pad ? (unsigned short)0 : f2b(u1);
                unsigned short ss = pad ? (unsigned short)0 : f2b(s);
                int pxblk = 4 * (yo - 1) + c;
                sB[(size_t)pxblk * (TT * 64) + (size_t)t * 64 + l] = ss;
                us[buf][w][64 * c + l] = uu;
            }
            #pragma unroll
            for (int c = 0; c < 5; ++c) { r0[c] = r1[c]; r1[c] = r2[c]; }
        }
        if (i > 0) {
            // write out row yo-1: thread (px = tid>>1, half h = tid&1)
            const int buf = (i - 1) & 1;
            const int yw  = yo - 1;
            const int px  = tid >> 1;
            const int h   = tid & 1;
            bf16x4 vv;
            vv[0] = (short)us[buf][4 * h + 0][px];
            vv[1] = (short)us[buf][4 * h + 1][px];
            vv[2] = (short)us[buf][4 * h + 2][px];
            vv[3] = (short)us[buf][4 * h + 3][px];
            size_t e = ((size_t)(4 * (yw - 1) + (px >> 6)) * 64 + tg) * 512
                     + (size_t)(px & 63) * 8 + 4 * h;
            *(bf16x4*)(uT + e) = vv;
        }
        __syncthreads();
    }
}

// ---- kernel 3: MFMA GEMM + loss. grid 1020 px-blocks x 512 thr = 8 waves.
// NO LDS, NO barriers: A-frags are plain b128 loads from the tiled uT
// (t is register-contiguous by layout), shared across waves via L1.
// Wave w: i-tiles [32w,32w+32) and [480-32w,512-32w) — 9 chunk-visits each.
__global__ __launch_bounds__(512, 4)
void mainker(const unsigned short* __restrict__ uT,
             const unsigned short* __restrict__ sB,
             const unsigned short* __restrict__ Mb,
             float* __restrict__ d_out)
{
    __shared__ float red[8];
    const int tid = threadIdx.x, w = tid >> 6, lane = tid & 63;
    const int lr = lane & 15, lg = lane >> 4;
    const int pb = blockIdx.x;
    const unsigned short* ut = uT + (size_t)pb * 32768;
    const unsigned short* sb = sB + (size_t)pb * (TT * 64);
    const int i00 = 32 * w, i01 = 480 - 32 * w;
    const int ce0 = w >> 1, ce1 = (511 - 32 * w) >> 6;

    f32x4 acc0[4][2], acc1[4][2];
    #pragma unroll
    for (int a = 0; a < 4; ++a) {
        acc0[a][0] = (f32x4)0.f; acc0[a][1] = (f32x4)0.f;
        acc1[a][0] = (f32x4)0.f; acc1[a][1] = (f32x4)0.f;
    }

    float lsum = 0.f;
    for (int c = 0; c < 8; ++c) {
        const bool h0 = (c <= ce0), h1 = (c <= ce1);
        if (h0 | h1) {
            #pragma unroll
            for (int ks = 0; ks < 2; ++ks) {
                const int kof = 64 * c + 32 * ks + 8 * lg;
                bf16x8 af[4];
                #pragma unroll
                for (int mi = 0; mi < 4; ++mi)
                    af[mi] = *(const bf16x8*)(ut + (size_t)(8 * c + 4 * ks + lg) * 512
                                              + (16 * mi + lr) * 8);
                if (h0) {
                    const unsigned short* mp = Mb + (size_t)(i00 + lr) * TT + kof;
                    bf16x8 b0 = *(const bf16x8*)mp;
                    bf16x8 b1 = *(const bf16x8*)(mp + 16 * TT);
                    #pragma unroll
                    for (int mi = 0; mi < 4; ++mi) {
                        acc0[mi][0] = __builtin_amdgcn_mfma_f32_16x16x32_bf16(af[mi], b0, acc0[mi][0], 0, 0, 0);
                        acc0[mi][1] = __builtin_amdgcn_mfma_f32_16x16x32_bf16(af[mi], b1, acc0[mi][1], 0, 0, 0);
                    }
                }
                if (h1) {
                    const unsigned short* mp = Mb + (size_t)(i01 + lr) * TT + kof;
                    bf16x8 b0 = *(const bf16x8*)mp;
                    bf16x8 b1 = *(const bf16x8*)(mp + 16 * TT);
                    #pragma unroll
                    for (int mi = 0; mi < 4; ++mi) {
                        acc1[mi][0] = __builtin_amdgcn_mfma_f32_16x16x32_bf16(af[mi], b0, acc1[mi][0], 0, 0, 0);
                        acc1[mi][1] = __builtin_amdgcn_mfma_f32_16x16x32_bf16(af[mi], b1, acc1[mi][1], 0, 0, 0);
                    }
                }
            }
        }
        if (c == ce0) {
            #pragma unroll
            for (int mi = 0; mi < 4; ++mi)
                #pragma unroll
                for (int nj = 0; nj < 2; ++nj) {
                    int tt = i00 + 16 * nj + lr;
                    bf16x4 sv = *(const bf16x4*)(sb + (size_t)tt * 64 + 16 * mi + 4 * lg);
                    #pragma unroll
                    for (int r = 0; r < 4; ++r) {
                        float res = SCALE * acc0[mi][nj][r] + b2f((unsigned short)sv[r]);
                        lsum += res * res;
                    }
                }
        }
        if (c == ce1) {
            #pragma unroll
            for (int mi = 0; mi < 4; ++mi)
                #pragma unroll
                for (int nj = 0; nj < 2; ++nj) {
                    int tt = i01 + 16 * nj + lr;
                    bf16x4 sv = *(const bf16x4*)(sb + (size_t)tt * 64 + 16 * mi + 4 * lg);
                    #pragma unroll
                    for (int r = 0; r < 4; ++r) {
                        float res = SCALE * acc1[mi][nj][r] + b2f((unsigned short)sv[r]);
                        lsum += res * res;
                    }
                }
        }
    }

    // reduce: wave shfl -> LDS -> one atomic per block
    #pragma unroll
    for (int off = 32; off > 0; off >>= 1)
        lsum += __shfl_down(lsum, off, 64);
    if (lane == 0) red[w] = lsum;
    __syncthreads();
    if (tid == 0) {
        float tot = 0.f;
        #pragma unroll
        for (int q = 0; q < 8; ++q) tot += red[q];
        atomicAdd(d_out, tot * (1.0f / 33292800.0f));
    }
}

extern "C" void kernel_launch(void* const* d_in, const int* in_sizes, int n_in,
                              void* d_out, int out_size, void* d_ws, size_t ws_size,
                              hipStream_t stream)
{
    const float* uin  = (const float*)d_in[0];
    const float* f1   = (const float*)d_in[1];
    const float* lapk = (const float*)d_in[2];
    float* out = (float*)d_out;

    unsigned short* Mb = (unsigned short*)d_ws;                    // 512 KB
    unsigned short* uT = Mb + (size_t)TT * TT;                     // 66.8 MB tiled
    unsigned short* sB = uT + (size_t)1020 * 32768;                // 66.8 MB
    // total exactly 128 MiB

    hipMemsetAsync(out, 0, sizeof(float), stream);
    build_m<<<dim3(TT), 256, 0, stream>>>(Mb);
    prestage<<<dim3(256), 512, 0, stream>>>(uin, f1, lapk, uT, sB);
    mainker<<<dim3(1020), 512, 0, stream>>>(uT, sB, Mb, out);
}

// Round 14
// 95.557 us; speedup vs baseline: 1.8384x; 1.8384x over previous
//
#include <hip/hip_runtime.h>

#define TT    512
#define WW    257
#define HWSZ  (WW*WW)          // 66049
#define IMG2  (2*HWSZ)         // time stride in `output` (2 channels)
#define SCALE 3.5682482323055424f   // DT^-0.5 / gamma(1.5)
#define KD    163.84f               // KAPPA / DX^2

typedef short bf16x8 __attribute__((ext_vector_type(8)));
typedef short bf16x4 __attribute__((ext_vector_type(4)));
typedef float f32x4  __attribute__((ext_vector_type(4)));
typedef unsigned int u32x4 __attribute__((ext_vector_type(4)));

__device__ __forceinline__ float wf(int j) {
    return sqrtf((float)(j + 1)) - sqrtf((float)j);
}
__device__ __forceinline__ float mcoef(int i, int k) {
    if (i == 0 || k > i) return 0.f;
    if (k == i) return 1.f;
    if (k == 0) return -wf(i - 1);
    int d = i - k;
    return wf(d) - wf(d - 1);
}
__device__ __forceinline__ unsigned short f2b(float f) {
    unsigned u = __float_as_uint(f);
    return (unsigned short)((u + 0x7FFFu + ((u >> 16) & 1u)) >> 16);
}
__device__ __forceinline__ float b2f(unsigned short h) {
    return __uint_as_float(((unsigned)h) << 16);
}

// ---- kernel 1: M as bf16 [512][512] (L2-resident)
__global__ __launch_bounds__(256)
void build_m(unsigned short* __restrict__ M) {
    int i = blockIdx.x;
    for (int k = threadIdx.x; k < TT; k += 256)
        M[i * TT + k] = f2b(mcoef(i, k));
}

// ---- fused Y=2: block = (y-pair, 64 px) x all 512 t. grid 512, 8 waves.
// u logical traffic 270 MB (vs 400), M logical 139 MB (vs 277), f1 133.
// Wave w: i-tiles [32w,32w+32) and [480-32w,512-32w) over 128 px' = 17 subs.
__global__ __launch_bounds__(512, 2)
void fused(const float* __restrict__ uin, const float* __restrict__ f1p,
           const float* __restrict__ lapk, const unsigned short* __restrict__ Mb,
           float* __restrict__ d_out)
{
    __shared__ unsigned short uS[2][128][64];   // [buf][px'][t-local] swizzled 16B segs
    __shared__ unsigned short sS[2][64][136];   // [buf][t-local][px' + pad]
    __shared__ float red[8];

    const int tid  = threadIdx.x;
    const int w    = tid >> 6;
    const int lane = tid & 63;
    const int lr   = lane & 15;
    const int lg   = lane >> 4;

    // XCD-bijective: consecutive wg = consecutive ypb within an x-tile
    const int bid = blockIdx.x;                 // 512
    const int wg  = (bid & 7) * 64 + (bid >> 3);
    const int xt  = wg >> 7;                    // 0..3
    const int ypb = wg & 127;                   // 0..127
    const int Y0  = 1 + 2 * ypb;                // first output row (second = Y0+1)
    const int c0  = xt * 64;
    const bool validB = (Y0 + 1) <= 255;

    const float ka = lapk[0], kb = lapk[1], kc = lapk[4];

    f32x4 acc0[8][2], acc1[8][2];
    #pragma unroll
    for (int a = 0; a < 8; ++a) {
        acc0[a][0] = (f32x4)0.f; acc0[a][1] = (f32x4)0.f;
        acc1[a][0] = (f32x4)0.f; acc1[a][1] = (f32x4)0.f;
    }

    const bool pad = (c0 + lane) == 255;        // image x == 256 (pad column)
    const int  i00 = 32 * w;
    const int  i01 = 480 - 32 * w;
    const int  ec0 = w >> 1;
    const int  ec1 = (15 - w) >> 1;
    float lsum = 0.f;

    // single PF buffer: rows Y0-1..Y0+2 (a0..a3), f1 rows Y0,Y0+1, edge gather
    float a0[8], a1[8], a2[8], a3[8], fA[8], fB[8], ee;
    // edge map: lane = 8*tl + 4*side + rj  (tl = t-local, rj = row offset 0..3)
    const int tl = lane >> 3, code = lane & 7, side = code >> 2, rj = code & 3;
    const size_t geoff = (size_t)tl * IMG2 + (size_t)(Y0 - 1 + rj) * WW
                       + (side ? c0 + 65 : c0);

    auto LOADR = [&](int c) {
        const int tb = 64 * c + 8 * w;
        const float* pu = uin + (size_t)tb * IMG2 + (size_t)(Y0 - 1) * WW + (c0 + 1) + lane;
        const float* pf = f1p + (size_t)tb * HWSZ + (size_t)Y0 * WW + (c0 + 1) + lane;
        #pragma unroll
        for (int rr = 0; rr < 8; ++rr) {
            const float* qu = pu + (size_t)rr * IMG2;
            a0[rr] = qu[0]; a1[rr] = qu[WW]; a2[rr] = qu[2 * WW]; a3[rr] = qu[3 * WW];
            fA[rr] = pf[(size_t)rr * HWSZ];
            fB[rr] = pf[(size_t)rr * HWSZ + WW];
        }
        ee = uin[(size_t)tb * IMG2 + geoff];
    };

    auto STAGE = [&](int b) {
        // Qe at lane 8tl+4side+rj = edge Q starting at row rj (valid rj<=1)
        float e1  = __shfl(ee, lane + 1, 64);
        float e2  = __shfl(ee, lane + 2, 64);
        float QeX = fmaf(ka, ee + e2, kb * e1);
        u32x4 upA, upB;
        #pragma unroll
        for (int rr = 0; rr < 8; ++rr) {
            float PA = a0[rr] + a2[rr];
            float QA = fmaf(ka, PA, kb * a1[rr]);
            float RA = fmaf(kb, PA, kc * a1[rr]);
            float PB = a1[rr] + a3[rr];
            float QB = fmaf(ka, PB, kb * a2[rr]);
            float RB = fmaf(kb, PB, kc * a2[rr]);
            float qmA = __shfl(QA, lane - 1, 64), qpA = __shfl(QA, lane + 1, 64);
            float qmB = __shfl(QB, lane - 1, 64), qpB = __shfl(QB, lane + 1, 64);
            float eA0 = __shfl(QeX, 8 * rr,     64), eA1 = __shfl(QeX, 8 * rr + 4, 64);
            float eB0 = __shfl(QeX, 8 * rr + 1, 64), eB1 = __shfl(QeX, 8 * rr + 5, 64);
            if (lane == 0)  { qmA = eA0; qmB = eB0; }
            if (lane == 63) { qpA = eA1; qpB = eB1; }
            float lapA = qmA + qpA + RA;
            float lapB = qmB + qpB + RB;
            float sA = a1[rr] - fmaf(KD, lapA, fA[rr]);
            float sB_ = a2[rr] - fmaf(KD, lapB, fB[rr]);
            unsigned short uAv = pad ? (unsigned short)0 : f2b(a1[rr]);
            unsigned short sAv = pad ? (unsigned short)0 : f2b(sA);
            unsigned short uBv = (pad || !validB) ? (unsigned short)0 : f2b(a2[rr]);
            unsigned short sBv = (pad || !validB) ? (unsigned short)0 : f2b(sB_);
            sS[b][8 * w + rr][lane]      = sAv;
            sS[b][8 * w + rr][64 + lane] = sBv;
            if (rr & 1) { upA[rr >> 1] |= ((unsigned)uAv) << 16; upB[rr >> 1] |= ((unsigned)uBv) << 16; }
            else        { upA[rr >> 1]  = (unsigned)uAv;         upB[rr >> 1]  = (unsigned)uBv; }
        }
        *(u32x4*)&uS[b][lane]     [(w ^ (lane & 7)) * 8] = upA;
        *(u32x4*)&uS[b][64 + lane][(w ^ (lane & 7)) * 8] = upB;
    };

    auto EPI = [&](f32x4 (&acc)[8][2], int b, int lbase) {
        #pragma unroll
        for (int mi = 0; mi < 8; ++mi)
            #pragma unroll
            for (int nj = 0; nj < 2; ++nj) {
                bf16x4 sv = *(const bf16x4*)&sS[b][lbase + 16 * nj + lr][16 * mi + 4 * lg];
                #pragma unroll
                for (int r = 0; r < 4; ++r) {
                    float res = SCALE * acc[mi][nj][r] + b2f((unsigned short)sv[r]);
                    lsum += res * res;
                }
            }
    };

    LOADR(0);
    for (int c = 0; c < 8; ++c) {
        const int b = c & 1;

        // M preload FIRST (oldest) — clamped so count is uniform; auto-waits at
        // STAGE/MFMA then never drain the newer 49-load burst.
        bf16x8 m0a[2], m0b[2], m1a[2], m1b[2];
        #pragma unroll
        for (int sub = 0; sub < 2; ++sub) {
            const int s_  = 2 * c + sub;
            const int k0  = 32 * (s_ <= w ? s_ : w);
            const int k1  = 32 * (s_ <= 15 - w ? s_ : 15 - w);
            const unsigned short* mp0 = Mb + (size_t)(i00 + lr) * TT + k0 + 8 * lg;
            const unsigned short* mp1 = Mb + (size_t)(i01 + lr) * TT + k1 + 8 * lg;
            m0a[sub] = *(const bf16x8*)mp0; m0b[sub] = *(const bf16x8*)(mp0 + 16 * TT);
            m1a[sub] = *(const bf16x8*)mp1; m1b[sub] = *(const bf16x8*)(mp1 + 16 * TT);
        }
        __builtin_amdgcn_sched_barrier(0);

        STAGE(b);                       // consumes PF(c); auto-wait leaves M in flight
        if (c < 7) LOADR(c + 1);        // 49-load burst, drains across barrier+MFMA

        __builtin_amdgcn_sched_barrier(0);
        asm volatile("s_waitcnt lgkmcnt(0)");
        __builtin_amdgcn_sched_barrier(0);
        __builtin_amdgcn_s_barrier();
        __builtin_amdgcn_sched_barrier(0);

        #pragma unroll
        for (int sub = 0; sub < 2; ++sub) {
            const int s_ = 2 * c + sub;
            if (s_ <= w) {
                #pragma unroll
                for (int mi = 0; mi < 8; ++mi) {
                    bf16x8 a = *(const bf16x8*)&uS[b][16 * mi + lr][(((4 * sub + lg) ^ (lr & 7))) * 8];
                    acc0[mi][0] = __builtin_amdgcn_mfma_f32_16x16x32_bf16(a, m0a[sub], acc0[mi][0], 0, 0, 0);
                    acc0[mi][1] = __builtin_amdgcn_mfma_f32_16x16x32_bf16(a, m0b[sub], acc0[mi][1], 0, 0, 0);
                }
            }
            if (s_ <= 15 - w) {
                #pragma unroll
                for (int mi = 0; mi < 8; ++mi) {
                    bf16x8 a = *(const bf16x8*)&uS[b][16 * mi + lr][(((4 * sub + lg) ^ (lr & 7))) * 8];
                    acc1[mi][0] = __builtin_amdgcn_mfma_f32_16x16x32_bf16(a, m1a[sub], acc1[mi][0], 0, 0, 0);
                    acc1[mi][1] = __builtin_amdgcn_mfma_f32_16x16x32_bf16(a, m1b[sub], acc1[mi][1], 0, 0, 0);
                }
            }
        }

        if (c == ec0) EPI(acc0, b, 32 * (w & 1));
        if (c == ec1) EPI(acc1, b, 32 * ((w + 1) & 1));
    }

    // ---- reduce: wave shfl -> LDS -> one atomic per block
    #pragma unroll
    for (int off = 32; off > 0; off >>= 1)
        lsum += __shfl_down(lsum, off, 64);
    if (lane == 0) red[w] = lsum;
    __syncthreads();
    if (tid == 0) {
        float tot = 0.f;
        #pragma unroll
        for (int q = 0; q < 8; ++q) tot += red[q];
        atomicAdd(d_out, tot * (1.0f / 33292800.0f));
    }
}

extern "C" void kernel_launch(void* const* d_in, const int* in_sizes, int n_in,
                              void* d_out, int out_size, void* d_ws, size_t ws_size,
                              hipStream_t stream)
{
    const float* uin  = (const float*)d_in[0];
    const float* f1   = (const float*)d_in[1];
    const float* lapk = (const float*)d_in[2];
    float* out = (float*)d_out;

    unsigned short* Mb = (unsigned short*)d_ws;   // 512 KB

    hipMemsetAsync(out, 0, sizeof(float), stream);
    build_m<<<dim3(TT), 256, 0, stream>>>(Mb);
    fused<<<dim3(512), 512, 0, stream>>>(uin, f1, lapk, Mb, out);
}

// Round 15
// 95.336 us; speedup vs baseline: 1.8427x; 1.0023x over previous
//
#include <hip/hip_runtime.h>

#define TT    512
#define WW    257
#define HWSZ  (WW*WW)          // 66049
#define IMG2  (2*HWSZ)         // time stride in `output` (2 channels)
#define SCALE 3.5682482323055424f   // DT^-0.5 / gamma(1.5)
#define KD    163.84f               // KAPPA / DX^2

typedef short bf16x8 __attribute__((ext_vector_type(8)));
typedef short bf16x4 __attribute__((ext_vector_type(4)));
typedef float f32x4  __attribute__((ext_vector_type(4)));
typedef unsigned int u32x4 __attribute__((ext_vector_type(4)));

__device__ __forceinline__ float wf(int j) {
    return sqrtf((float)(j + 1)) - sqrtf((float)j);
}
__device__ __forceinline__ float mcoef(int i, int k) {
    if (i == 0 || k > i) return 0.f;
    if (k == i) return 1.f;
    if (k == 0) return -wf(i - 1);
    int d = i - k;
    return wf(d) - wf(d - 1);
}
__device__ __forceinline__ unsigned short f2b(float f) {
    unsigned u = __float_as_uint(f);
    return (unsigned short)((u + 0x7FFFu + ((u >> 16) & 1u)) >> 16);
}
__device__ __forceinline__ float b2f(unsigned short h) {
    return __uint_as_float(((unsigned)h) << 16);
}

// ---- kernel 1: M as bf16 [512][512] (L2-resident); also zeroes d_out
__global__ __launch_bounds__(256)
void build_m(unsigned short* __restrict__ M, float* __restrict__ d_out) {
    int i = blockIdx.x;
    if (i == 0 && threadIdx.x == 0) *d_out = 0.f;
    for (int k = threadIdx.x; k < TT; k += 256)
        M[i * TT + k] = f2b(mcoef(i, k));
}

// ---- fused Y=2: block = (y-pair, 64 px) x all 512 t. grid 512, 8 waves.
// Wave w: i-tiles [32w,32w+32) and [480-32w,512-32w) over 128 px' = 17 subs.
// M loads predicated (saves 40% of M logical bytes); setprio around MFMA.
__global__ __launch_bounds__(512, 2)
void fused(const float* __restrict__ uin, const float* __restrict__ f1p,
           const float* __restrict__ lapk, const unsigned short* __restrict__ Mb,
           float* __restrict__ d_out)
{
    __shared__ unsigned short uS[2][128][64];   // [buf][px'][t-local] swizzled 16B segs
    __shared__ unsigned short sS[2][64][136];   // [buf][t-local][px' + pad]
    __shared__ float red[8];

    const int tid  = threadIdx.x;
    const int w    = tid >> 6;
    const int lane = tid & 63;
    const int lr   = lane & 15;
    const int lg   = lane >> 4;

    // XCD-bijective: consecutive wg = consecutive ypb within an x-tile
    const int bid = blockIdx.x;                 // 512
    const int wg  = (bid & 7) * 64 + (bid >> 3);
    const int xt  = wg >> 7;                    // 0..3
    const int ypb = wg & 127;                   // 0..127
    const int Y0  = 1 + 2 * ypb;                // first output row (second = Y0+1)
    const int c0  = xt * 64;
    const bool validB = (Y0 + 1) <= 255;

    const float ka = lapk[0], kb = lapk[1], kc = lapk[4];

    f32x4 acc0[8][2], acc1[8][2];
    #pragma unroll
    for (int a = 0; a < 8; ++a) {
        acc0[a][0] = (f32x4)0.f; acc0[a][1] = (f32x4)0.f;
        acc1[a][0] = (f32x4)0.f; acc1[a][1] = (f32x4)0.f;
    }

    const bool pad = (c0 + lane) == 255;        // image x == 256 (pad column)
    const int  i00 = 32 * w;
    const int  i01 = 480 - 32 * w;
    const int  ec0 = w >> 1;
    const int  ec1 = (15 - w) >> 1;
    float lsum = 0.f;

    // single PF buffer: rows Y0-1..Y0+2 (a0..a3), f1 rows Y0,Y0+1, edge gather
    float a0[8], a1[8], a2[8], a3[8], fA[8], fB[8], ee;
    // edge map: lane = 8*tl + 4*side + rj  (tl = t-local, rj = row offset 0..3)
    const int tl = lane >> 3, code = lane & 7, side = code >> 2, rj = code & 3;
    const size_t geoff = (size_t)tl * IMG2 + (size_t)(Y0 - 1 + rj) * WW
                       + (side ? c0 + 65 : c0);

    auto LOADR = [&](int c) {
        const int tb = 64 * c + 8 * w;
        const float* pu = uin + (size_t)tb * IMG2 + (size_t)(Y0 - 1) * WW + (c0 + 1) + lane;
        const float* pf = f1p + (size_t)tb * HWSZ + (size_t)Y0 * WW + (c0 + 1) + lane;
        #pragma unroll
        for (int rr = 0; rr < 8; ++rr) {
            const float* qu = pu + (size_t)rr * IMG2;
            a0[rr] = qu[0]; a1[rr] = qu[WW]; a2[rr] = qu[2 * WW]; a3[rr] = qu[3 * WW];
            fA[rr] = pf[(size_t)rr * HWSZ];
            fB[rr] = pf[(size_t)rr * HWSZ + WW];
        }
        ee = uin[(size_t)tb * IMG2 + geoff];
    };

    auto STAGE = [&](int b) {
        // Qe at lane 8tl+4side+rj = edge Q starting at row rj (valid rj<=1)
        float e1  = __shfl(ee, lane + 1, 64);
        float e2  = __shfl(ee, lane + 2, 64);
        float QeX = fmaf(ka, ee + e2, kb * e1);
        u32x4 upA, upB;
        #pragma unroll
        for (int rr = 0; rr < 8; ++rr) {
            float PA = a0[rr] + a2[rr];
            float QA = fmaf(ka, PA, kb * a1[rr]);
            float RA = fmaf(kb, PA, kc * a1[rr]);
            float PB = a1[rr] + a3[rr];
            float QB = fmaf(ka, PB, kb * a2[rr]);
            float RB = fmaf(kb, PB, kc * a2[rr]);
            float qmA = __shfl(QA, lane - 1, 64), qpA = __shfl(QA, lane + 1, 64);
            float qmB = __shfl(QB, lane - 1, 64), qpB = __shfl(QB, lane + 1, 64);
            float eA0 = __shfl(QeX, 8 * rr,     64), eA1 = __shfl(QeX, 8 * rr + 4, 64);
            float eB0 = __shfl(QeX, 8 * rr + 1, 64), eB1 = __shfl(QeX, 8 * rr + 5, 64);
            if (lane == 0)  { qmA = eA0; qmB = eB0; }
            if (lane == 63) { qpA = eA1; qpB = eB1; }
            float lapA = qmA + qpA + RA;
            float lapB = qmB + qpB + RB;
            float sA = a1[rr] - fmaf(KD, lapA, fA[rr]);
            float sB_ = a2[rr] - fmaf(KD, lapB, fB[rr]);
            unsigned short uAv = pad ? (unsigned short)0 : f2b(a1[rr]);
            unsigned short sAv = pad ? (unsigned short)0 : f2b(sA);
            unsigned short uBv = (pad || !validB) ? (unsigned short)0 : f2b(a2[rr]);
            unsigned short sBv = (pad || !validB) ? (unsigned short)0 : f2b(sB_);
            sS[b][8 * w + rr][lane]      = sAv;
            sS[b][8 * w + rr][64 + lane] = sBv;
            if (rr & 1) { upA[rr >> 1] |= ((unsigned)uAv) << 16; upB[rr >> 1] |= ((unsigned)uBv) << 16; }
            else        { upA[rr >> 1]  = (unsigned)uAv;         upB[rr >> 1]  = (unsigned)uBv; }
        }
        *(u32x4*)&uS[b][lane]     [(w ^ (lane & 7)) * 8] = upA;
        *(u32x4*)&uS[b][64 + lane][(w ^ (lane & 7)) * 8] = upB;
    };

    auto EPI = [&](f32x4 (&acc)[8][2], int b, int lbase) {
        #pragma unroll
        for (int mi = 0; mi < 8; ++mi)
            #pragma unroll
            for (int nj = 0; nj < 2; ++nj) {
                bf16x4 sv = *(const bf16x4*)&sS[b][lbase + 16 * nj + lr][16 * mi + 4 * lg];
                #pragma unroll
                for (int r = 0; r < 4; ++r) {
                    float res = SCALE * acc[mi][nj][r] + b2f((unsigned short)sv[r]);
                    lsum += res * res;
                }
            }
    };

    LOADR(0);
    for (int c = 0; c < 8; ++c) {
        const int b = c & 1;

        // M preload (PREDICATED — only tiles this wave still accumulates).
        // Issued before the 49-load burst so auto-waits never drain it.
        bf16x8 m0a[2], m0b[2], m1a[2], m1b[2];
        #pragma unroll
        for (int sub = 0; sub < 2; ++sub) {
            const int s_ = 2 * c + sub;
            if (s_ <= w) {
                const unsigned short* mp0 = Mb + (size_t)(i00 + lr) * TT + 32 * s_ + 8 * lg;
                m0a[sub] = *(const bf16x8*)mp0; m0b[sub] = *(const bf16x8*)(mp0 + 16 * TT);
            }
            if (s_ <= 15 - w) {
                const unsigned short* mp1 = Mb + (size_t)(i01 + lr) * TT + 32 * s_ + 8 * lg;
                m1a[sub] = *(const bf16x8*)mp1; m1b[sub] = *(const bf16x8*)(mp1 + 16 * TT);
            }
        }
        __builtin_amdgcn_sched_barrier(0);

        STAGE(b);                       // consumes PF(c); auto-wait leaves M in flight
        if (c < 7) LOADR(c + 1);        // 49-load burst, drains across barrier+MFMA

        __builtin_amdgcn_sched_barrier(0);
        asm volatile("s_waitcnt lgkmcnt(0)");
        __builtin_amdgcn_sched_barrier(0);
        __builtin_amdgcn_s_barrier();
        __builtin_amdgcn_sched_barrier(0);

        __builtin_amdgcn_s_setprio(1);
        #pragma unroll
        for (int sub = 0; sub < 2; ++sub) {
            const int s_ = 2 * c + sub;
            if (s_ <= w) {
                #pragma unroll
                for (int mi = 0; mi < 8; ++mi) {
                    bf16x8 a = *(const bf16x8*)&uS[b][16 * mi + lr][(((4 * sub + lg) ^ (lr & 7))) * 8];
                    acc0[mi][0] = __builtin_amdgcn_mfma_f32_16x16x32_bf16(a, m0a[sub], acc0[mi][0], 0, 0, 0);
                    acc0[mi][1] = __builtin_amdgcn_mfma_f32_16x16x32_bf16(a, m0b[sub], acc0[mi][1], 0, 0, 0);
                }
            }
            if (s_ <= 15 - w) {
                #pragma unroll
                for (int mi = 0; mi < 8; ++mi) {
                    bf16x8 a = *(const bf16x8*)&uS[b][16 * mi + lr][(((4 * sub + lg) ^ (lr & 7))) * 8];
                    acc1[mi][0] = __builtin_amdgcn_mfma_f32_16x16x32_bf16(a, m1a[sub], acc1[mi][0], 0, 0, 0);
                    acc1[mi][1] = __builtin_amdgcn_mfma_f32_16x16x32_bf16(a, m1b[sub], acc1[mi][1], 0, 0, 0);
                }
            }
        }
        __builtin_amdgcn_s_setprio(0);

        if (c == ec0) EPI(acc0, b, 32 * (w & 1));
        if (c == ec1) EPI(acc1, b, 32 * ((w + 1) & 1));
    }

    // ---- reduce: wave shfl -> LDS -> one atomic per block
    #pragma unroll
    for (int off = 32; off > 0; off >>= 1)
        lsum += __shfl_down(lsum, off, 64);
    if (lane == 0) red[w] = lsum;
    __syncthreads();
    if (tid == 0) {
        float tot = 0.f;
        #pragma unroll
        for (int q = 0; q < 8; ++q) tot += red[q];
        atomicAdd(d_out, tot * (1.0f / 33292800.0f));
    }
}

extern "C" void kernel_launch(void* const* d_in, const int* in_sizes, int n_in,
                              void* d_out, int out_size, void* d_ws, size_t ws_size,
                              hipStream_t stream)
{
    const float* uin  = (const float*)d_in[0];
    const float* f1   = (const float*)d_in[1];
    const float* lapk = (const float*)d_in[2];
    float* out = (float*)d_out;

    unsigned short* Mb = (unsigned short*)d_ws;   // 512 KB

    build_m<<<dim3(TT), 256, 0, stream>>>(Mb, out);
    fused<<<dim3(512), 512, 0, stream>>>(uin, f1, lapk, Mb, out);
}